// Round 2
// baseline (37.226 us; speedup 1.0000x reference)
//
#include <hip/hip_runtime.h>
#include <math.h>

#define IN_SIZE 448
#define OUT_SIZE 224

__device__ __forceinline__ float sig10(float v) {
    // jax.nn.sigmoid(10*v) = 1/(1+exp(-10v)); expf(+inf)->inf -> result 0. Safe.
    return 1.0f / (1.0f + expf(-10.0f * v));
}

__global__ __launch_bounds__(256) void attention_crop_kernel(
    const float* __restrict__ images,   // [B,3,448,448]
    const float* __restrict__ locs,     // [B,3]
    float* __restrict__ out)            // [B,3,224,224]
{
    const int idx = blockIdx.x * 256 + threadIdx.x;        // over B*224*224
    const int b   = idx / (OUT_SIZE * OUT_SIZE);           // each block maps to one b (50176 % 256 == 0)
    const int rem = idx - b * (OUT_SIZE * OUT_SIZE);
    const int i   = rem / OUT_SIZE;                        // output row  -> r coordinate
    const int j   = rem - i * OUT_SIZE;                    // output col  -> c coordinate

    // ---- per-sample scalars (wave-uniform: whole block shares b) ----
    float tx = locs[b * 3 + 0];
    float ty = locs[b * 3 + 1];
    float tl = locs[b * 3 + 2];
    const float third = 448.0f / 3.0f;
    tl = fmaxf(tl, third);
    tx = fminf(fmaxf(tx, tl), 448.0f - tl);
    ty = fminf(fmaxf(ty, tl), 448.0f - tl);

    const float w_off_f = fminf(fmaxf(floorf(tx - tl), 0.0f), 448.0f);
    const float h_off_f = fminf(fmaxf(floorf(ty - tl), 0.0f), 448.0f);
    const float w_end_f = fminf(fmaxf(floorf(tx + tl), 0.0f), 448.0f);
    const float h_end_f = fminf(fmaxf(floorf(ty + tl), 0.0f), 448.0f);
    const int w_off = (int)w_off_f;
    const int h_off = (int)h_off_f;
    const int w_end = (int)w_end_f;
    const int h_end = (int)h_end_f;

    // ---- sample coordinates (match jnp: int32 span, f32 t) ----
    const float ti = (float)i / 223.0f;
    const float tj = (float)j / 223.0f;
    const float r = w_off_f + ti * (float)(w_end - 1 - w_off);
    const float c = h_off_f + tj * (float)(h_end - 1 - h_off);
    const float r0f = floorf(r);
    const float c0f = floorf(c);
    const int r0 = (int)r0f;
    const int c0 = (int)c0f;
    const int r1 = min(r0 + 1, IN_SIZE - 1);
    const int c1 = min(c0 + 1, IN_SIZE - 1);
    const float fr = r - r0f;
    const float fc = c - c0f;

    // ---- separable soft-mask values at the 4 integer taps ----
    const float mr0 = sig10((float)(r0 - w_off)) - sig10((float)(r0 - w_end));
    const float mr1 = sig10((float)(r1 - w_off)) - sig10((float)(r1 - w_end));
    const float mc0 = sig10((float)(c0 - h_off)) - sig10((float)(c0 - h_end));
    const float mc1 = sig10((float)(c1 - h_off)) - sig10((float)(c1 - h_end));

    const float m00 = mr0 * mc0;
    const float m01 = mr0 * mc1;
    const float m10 = mr1 * mc0;
    const float m11 = mr1 * mc1;

    const size_t img_base = (size_t)b * 3 * IN_SIZE * IN_SIZE;
    const size_t out_base = (size_t)b * 3 * OUT_SIZE * OUT_SIZE;
    const int o00 = r0 * IN_SIZE + c0;
    const int o01 = r0 * IN_SIZE + c1;
    const int o10 = r1 * IN_SIZE + c0;
    const int o11 = r1 * IN_SIZE + c1;

#pragma unroll
    for (int ch = 0; ch < 3; ++ch) {
        const float* __restrict__ img = images + img_base + (size_t)ch * IN_SIZE * IN_SIZE;
        const float v00 = img[o00] * m00;
        const float v01 = img[o01] * m01;
        const float v10 = img[o10] * m10;
        const float v11 = img[o11] * m11;
        const float top = v00 * (1.0f - fc) + v01 * fc;
        const float bot = v10 * (1.0f - fc) + v11 * fc;
        const float res = top * (1.0f - fr) + bot * fr;
        out[out_base + (size_t)ch * OUT_SIZE * OUT_SIZE + (size_t)i * OUT_SIZE + j] = res;
    }
}

extern "C" void kernel_launch(void* const* d_in, const int* in_sizes, int n_in,
                              void* d_out, int out_size, void* d_ws, size_t ws_size,
                              hipStream_t stream) {
    const float* images = (const float*)d_in[0];   // [64,3,448,448] f32
    const float* locs   = (const float*)d_in[1];   // [64,3] f32
    float* out = (float*)d_out;                    // [64,3,224,224] f32

    const int B = in_sizes[1] / 3;                 // 64
    const int total = B * OUT_SIZE * OUT_SIZE;     // one thread per (b,i,j), 3 channels each
    const int block = 256;
    const int grid = (total + block - 1) / block;  // 12544
    attention_crop_kernel<<<grid, block, 0, stream>>>(images, locs, out);
}

// Round 3
// 30.470 us; speedup vs baseline: 1.2217x; 1.2217x over previous
//
#include <hip/hip_runtime.h>
#include <math.h>

#define IN_SIZE 448
#define OUT_SIZE 224

// jax.nn.sigmoid(10*d) at INTEGER d, branchless 5-case select.
// Exact f32 for |d|<=1; abs error < 2.1e-9 for |d|>=2 (sig10(±2)=1∓2.06e-9,
// which rounds to the same f32 as the limit for d>=2). Replaces expf + precise
// fdiv (~40 instrs, 3 transcendentals) with ~4 v_cndmask.
__device__ __forceinline__ float sig10i(int d) {
    const float neg = (d == -1) ? 4.5397868e-5f : 2.0611536e-9f;
    const float pos = (d == 0) ? 0.5f : ((d == 1) ? 0.99995458f : 1.0f);
    return (d < 0) ? neg : pos;
}

__global__ __launch_bounds__(256) void attention_crop_kernel(
    const float* __restrict__ images,   // [B,3,448,448]
    const float* __restrict__ locs,     // [B,3]
    float* __restrict__ out)            // [B,3,224,224]
{
    // XCD chunk swizzle: hardware round-robins blockIdx across 8 XCDs; remap so
    // each XCD gets a contiguous chunk of samples (per-sample 2.4 MB fits 4 MB L2).
    const int cpx = gridDim.x >> 3;                         // 12544/8 = 1568
    const int bid = (blockIdx.x & 7) * cpx + (blockIdx.x >> 3);

    const int idx = bid * 256 + threadIdx.x;                // over B*224*224
    const int b   = idx / (OUT_SIZE * OUT_SIZE);            // block maps to one b (50176 % 256 == 0)
    const int rem = idx - b * (OUT_SIZE * OUT_SIZE);
    const int i   = rem / OUT_SIZE;                         // output row  -> r coordinate
    const int j   = rem - i * OUT_SIZE;                     // output col  -> c coordinate

    // ---- per-sample scalars (wave-uniform) ----
    float tx = locs[b * 3 + 0];
    float ty = locs[b * 3 + 1];
    float tl = locs[b * 3 + 2];
    const float third = 448.0f / 3.0f;
    tl = fmaxf(tl, third);
    tx = fminf(fmaxf(tx, tl), 448.0f - tl);
    ty = fminf(fmaxf(ty, tl), 448.0f - tl);

    const float w_off_f = fminf(fmaxf(floorf(tx - tl), 0.0f), 448.0f);
    const float h_off_f = fminf(fmaxf(floorf(ty - tl), 0.0f), 448.0f);
    const float w_end_f = fminf(fmaxf(floorf(tx + tl), 0.0f), 448.0f);
    const float h_end_f = fminf(fmaxf(floorf(ty + tl), 0.0f), 448.0f);
    const int w_off = (int)w_off_f;
    const int h_off = (int)h_off_f;
    const int w_end = (int)w_end_f;
    const int h_end = (int)h_end_f;

    // ---- sample coordinates (match jnp: int32 span, f32 t) ----
    const float ti = (float)i / 223.0f;
    const float tj = (float)j / 223.0f;
    const float r = w_off_f + ti * (float)(w_end - 1 - w_off);
    const float c = h_off_f + tj * (float)(h_end - 1 - h_off);
    const float r0f = floorf(r);
    const float c0f = floorf(c);
    const int r0 = (int)r0f;
    const int c0 = (int)c0f;
    const int r1 = min(r0 + 1, IN_SIZE - 1);
    const int c1 = min(c0 + 1, IN_SIZE - 1);
    const float fr = r - r0f;
    const float fc = c - c0f;

    // ---- separable soft-mask values at the 4 integer taps (LUT, no expf) ----
    const float mr0 = sig10i(r0 - w_off) - sig10i(r0 - w_end);
    const float mr1 = sig10i(r1 - w_off) - sig10i(r1 - w_end);
    const float mc0 = sig10i(c0 - h_off) - sig10i(c0 - h_end);
    const float mc1 = sig10i(c1 - h_off) - sig10i(c1 - h_end);

    const float m00 = mr0 * mc0;
    const float m01 = mr0 * mc1;
    const float m10 = mr1 * mc0;
    const float m11 = mr1 * mc1;

    const size_t img_base = (size_t)b * 3 * IN_SIZE * IN_SIZE;
    const size_t out_base = (size_t)b * 3 * OUT_SIZE * OUT_SIZE;
    const int o00 = r0 * IN_SIZE + c0;
    const int o01 = r0 * IN_SIZE + c1;
    const int o10 = r1 * IN_SIZE + c0;
    const int o11 = r1 * IN_SIZE + c1;

#pragma unroll
    for (int ch = 0; ch < 3; ++ch) {
        const float* __restrict__ img = images + img_base + (size_t)ch * IN_SIZE * IN_SIZE;
        const float v00 = img[o00] * m00;
        const float v01 = img[o01] * m01;
        const float v10 = img[o10] * m10;
        const float v11 = img[o11] * m11;
        const float top = v00 * (1.0f - fc) + v01 * fc;
        const float bot = v10 * (1.0f - fc) + v11 * fc;
        const float res = top * (1.0f - fr) + bot * fr;
        // streaming store: don't let the 38.5 MB output evict L3-resident input
        __builtin_nontemporal_store(res,
            &out[out_base + (size_t)ch * OUT_SIZE * OUT_SIZE + (size_t)i * OUT_SIZE + j]);
    }
}

extern "C" void kernel_launch(void* const* d_in, const int* in_sizes, int n_in,
                              void* d_out, int out_size, void* d_ws, size_t ws_size,
                              hipStream_t stream) {
    const float* images = (const float*)d_in[0];   // [64,3,448,448] f32
    const float* locs   = (const float*)d_in[1];   // [64,3] f32
    float* out = (float*)d_out;                    // [64,3,224,224] f32

    const int B = in_sizes[1] / 3;                 // 64
    const int total = B * OUT_SIZE * OUT_SIZE;     // one thread per (b,i,j), 3 channels each
    const int block = 256;
    const int grid = (total + block - 1) / block;  // 12544 (divisible by 8 for the XCD swizzle)
    attention_crop_kernel<<<grid, block, 0, stream>>>(images, locs, out);
}